// Round 1
// baseline (437.113 us; speedup 1.0000x reference)
//
#include <hip/hip_runtime.h>

// ---------------------------------------------------------------------------
// MultiHeadAttention graph-attention kernel for MI355X (gfx950).
// Pipeline:
//   1. cvt_f32_bf16: nodes + weights -> bf16
//   2. gemm_bt<false>: Kl, Kr, Vl, Vr projections (bf16 MFMA, bf16 out)
//   3. edge_dot: translation[e] = dot(Kl[segL[e]], Kr[segR[e]]) / sqrt(C)
//   4. CSR build per side (count -> scan -> fill), no sort needed
//   5. node_msg: per-node online {max, exp-sum, weighted V accumulate} -> bf16
//   6. gemm_bt<true>: msg @ Wo^T + bo, LeakyReLU, fp32 -> d_out
// ---------------------------------------------------------------------------

#define C_DIM 512
#define TEMP_INV (1.0f / 22.627416997969522f)   // 1/sqrt(512)

using bf16x8 = __attribute__((ext_vector_type(8))) __bf16;  // MFMA A/B frag
using s16x8  = __attribute__((ext_vector_type(8))) short;   // raw 16B of bf16
using s16x4  = __attribute__((ext_vector_type(4))) short;
using f32x4  = __attribute__((ext_vector_type(4))) float;

__device__ __forceinline__ float bf2f(short u) {
    union { unsigned u; float f; } t;
    t.u = ((unsigned)(unsigned short)u) << 16;
    return t.f;
}
__device__ __forceinline__ short f2bf(float f) {
    union { float f; unsigned u; } t;
    t.f = f;
    unsigned r = t.u + 0x7FFFu + ((t.u >> 16) & 1u);  // RNE
    return (short)(r >> 16);
}

// --------------------------- fp32 -> bf16 convert ---------------------------
__global__ void cvt_f32_bf16(const float* __restrict__ in,
                             short* __restrict__ out, long n4) {
    long i = (long)blockIdx.x * blockDim.x + threadIdx.x;
    long stride = (long)gridDim.x * blockDim.x;
    for (; i < n4; i += stride) {
        float4 v = reinterpret_cast<const float4*>(in)[i];
        s16x4 o;
        o[0] = f2bf(v.x); o[1] = f2bf(v.y); o[2] = f2bf(v.z); o[3] = f2bf(v.w);
        reinterpret_cast<s16x4*>(out)[i] = o;
    }
}

// ------------------------------- bf16 GEMM ---------------------------------
// C[M,N] = A[M,K] @ B[N,K]^T. 128x128 tile, BK=32, 4 waves (2x2), each wave
// owns a 64x64 sub-tile = 4x4 fragments of 16x16x32 MFMA.
// EPI=false: C is bf16 (short*).  EPI=true: C is fp32, += bias, LeakyReLU.
template <bool EPI>
__global__ __launch_bounds__(256, 2)
void gemm_bt(const short* __restrict__ A, const short* __restrict__ B,
             void* __restrict__ Cp, const float* __restrict__ bias,
             int M, int N, int K) {
    __shared__ short As[128 * 32];
    __shared__ short Bs[128 * 32];

    const int tid  = threadIdx.x;
    const int lane = tid & 63;
    const int wid  = tid >> 6;
    const int bm   = blockIdx.x * 128;
    const int bn   = blockIdx.y * 128;
    const int wm   = (wid >> 1) * 64;
    const int wn   = (wid & 1) * 64;

    f32x4 acc[4][4] = {};

    const int lrow  = lane & 15;
    const int khalf = lane >> 4;  // 0..3, selects k-subblock of 8

    for (int k0 = 0; k0 < K; k0 += 32) {
        // ---- stage A,B tiles: 8KB each, 16B/lane via global_load_lds ----
#pragma unroll
        for (int i = 0; i < 2; ++i) {
            int c   = i * 256 + tid;       // 16B chunk id, 0..511
            int row = c >> 2;              // tile row (64B per row)
            int kb  = (c & 3) * 8;         // bf16 col within row
            int wave_chunk = i * 256 + (tid & ~63);  // wave-uniform LDS base
            {
                int grow = bm + row; if (grow >= M) grow = M - 1;
                const short* src = A + (size_t)grow * K + k0 + kb;
                __builtin_amdgcn_global_load_lds(
                    (__attribute__((address_space(1))) void*)src,
                    (__attribute__((address_space(3))) void*)((char*)As + wave_chunk * 16),
                    16, 0, 0);
            }
            {
                int grow = bn + row; if (grow >= N) grow = N - 1;
                const short* src = B + (size_t)grow * K + k0 + kb;
                __builtin_amdgcn_global_load_lds(
                    (__attribute__((address_space(1))) void*)src,
                    (__attribute__((address_space(3))) void*)((char*)Bs + wave_chunk * 16),
                    16, 0, 0);
            }
        }
        __syncthreads();

        bf16x8 af[4], bfr[4];
#pragma unroll
        for (int m = 0; m < 4; ++m)
            af[m] = *(const bf16x8*)&As[(wm + m * 16 + lrow) * 32 + khalf * 8];
#pragma unroll
        for (int n = 0; n < 4; ++n)
            bfr[n] = *(const bf16x8*)&Bs[(wn + n * 16 + lrow) * 32 + khalf * 8];

#pragma unroll
        for (int m = 0; m < 4; ++m)
#pragma unroll
            for (int n = 0; n < 4; ++n)
                acc[m][n] = __builtin_amdgcn_mfma_f32_16x16x32_bf16(
                    af[m], bfr[n], acc[m][n], 0, 0, 0);
        __syncthreads();
    }

    // ---- epilogue: D mapping col=lane&15, row=(lane>>4)*4+r  [m89] ----
    const int crow0 = (lane >> 4) * 4;
    const int ccol  = lane & 15;
#pragma unroll
    for (int m = 0; m < 4; ++m) {
#pragma unroll
        for (int n = 0; n < 4; ++n) {
            int col = bn + wn + n * 16 + ccol;
#pragma unroll
            for (int r = 0; r < 4; ++r) {
                int row = bm + wm + m * 16 + crow0 + r;
                if (row < M) {
                    float v = acc[m][n][r];
                    if (EPI) {
                        v += bias[col];
                        v = v >= 0.f ? v : 0.01f * v;   // LeakyReLU
                        ((float*)Cp)[(size_t)row * N + col] = v;
                    } else {
                        ((short*)Cp)[(size_t)row * N + col] = f2bf(v);
                    }
                }
            }
        }
    }
}

// --------------------------- per-edge dot product ---------------------------
// one wave per edge; 64 lanes x 8 bf16 = 512 channels
__global__ void edge_dot(const short* __restrict__ Kl, const short* __restrict__ Kr,
                         const int* __restrict__ segL, const int* __restrict__ segR,
                         float* __restrict__ s, int E) {
    int e = blockIdx.x * 4 + (threadIdx.x >> 6);
    if (e >= E) return;
    int lane = threadIdx.x & 63;
    size_t il = (size_t)segL[e] * C_DIM;
    size_t ir = (size_t)segR[e] * C_DIM;
    s16x8 a = *(const s16x8*)(Kl + il + lane * 8);
    s16x8 b = *(const s16x8*)(Kr + ir + lane * 8);
    float sum = 0.f;
#pragma unroll
    for (int j = 0; j < 8; ++j) sum += bf2f(a[j]) * bf2f(b[j]);
#pragma unroll
    for (int o = 32; o > 0; o >>= 1) sum += __shfl_xor(sum, o, 64);
    if (lane == 0) s[e] = sum * TEMP_INV;
}

// ------------------------------- CSR build ---------------------------------
__global__ void count_edges(const int* __restrict__ seg, int* __restrict__ cnt, int E) {
    int i = blockIdx.x * blockDim.x + threadIdx.x;
    int st = gridDim.x * blockDim.x;
    for (; i < E; i += st) atomicAdd(&cnt[seg[i]], 1);
}

__global__ void scan_kernel(const int* __restrict__ cnt, int* __restrict__ off, int n) {
    __shared__ int buf[1024];
    __shared__ int carry;
    int tid = threadIdx.x;
    if (tid == 0) { carry = 0; off[0] = 0; }
    __syncthreads();
    for (int base = 0; base < n; base += 1024) {
        int v = (base + tid < n) ? cnt[base + tid] : 0;
        buf[tid] = v;
        __syncthreads();
        for (int d = 1; d < 1024; d <<= 1) {
            int t = (tid >= d) ? buf[tid - d] : 0;
            __syncthreads();
            buf[tid] += t;
            __syncthreads();
        }
        if (base + tid < n) off[base + tid + 1] = carry + buf[tid];
        __syncthreads();
        if (tid == 0) carry += buf[1023];
        __syncthreads();
    }
}

__global__ void fill_csr(const int* __restrict__ seg, const int* __restrict__ off,
                         int* __restrict__ cur, int* __restrict__ lst, int E) {
    int i = blockIdx.x * blockDim.x + threadIdx.x;
    int st = gridDim.x * blockDim.x;
    for (; i < E; i += st) {
        int n = seg[i];
        int p = off[n] + atomicAdd(&cur[n], 1);
        lst[p] = i;
    }
}

// ------------------- per-node softmax + weighted V sum ----------------------
// one wave per node; lane owns 8 channels. Output bf16 (GEMM A input).
__global__ void node_msg(const int* __restrict__ off, const int* __restrict__ lst,
                         const int* __restrict__ otherSeg, const float* __restrict__ s,
                         const short* __restrict__ V, short* __restrict__ out, int Nn) {
    int n = blockIdx.x * 4 + (threadIdx.x >> 6);
    if (n >= Nn) return;
    int lane = threadIdx.x & 63;
    int beg = off[n], end = off[n + 1];
    short* orow = out + (size_t)n * C_DIM + lane * 8;
    if (beg == end) {  // empty segment: msg = 0 (reference yields 0 after bias/relu)
        s16x8 z = {};
        *(s16x8*)orow = z;
        return;
    }
    float m = -1e30f;
    for (int i = beg; i < end; ++i) m = fmaxf(m, s[lst[i]]);
    float acc[8] = {};
    float z = 0.f;
    for (int i = beg; i < end; ++i) {
        int e = lst[i];
        float w = __expf(s[e] - m);
        z += w;
        s16x8 v = *(const s16x8*)(V + (size_t)otherSeg[e] * C_DIM + lane * 8);
#pragma unroll
        for (int j = 0; j < 8; ++j) acc[j] += w * bf2f(v[j]);
    }
    float inv = 1.f / z;
    s16x8 ov;
#pragma unroll
    for (int j = 0; j < 8; ++j) ov[j] = f2bf(acc[j] * inv);
    *(s16x8*)orow = ov;
}

// ------------------------------- launcher ----------------------------------
extern "C" void kernel_launch(void* const* d_in, const int* in_sizes, int n_in,
                              void* d_out, int out_size, void* d_ws, size_t ws_size,
                              hipStream_t stream) {
    const float* node_left  = (const float*)d_in[0];
    const int*   segL       = (const int*)d_in[1];
    const float* node_right = (const float*)d_in[3];
    const int*   segR       = (const int*)d_in[4];
    const float* Wk         = (const float*)d_in[6];
    const float* Wv         = (const float*)d_in[7];
    const float* Wo         = (const float*)d_in[8];
    const float* bo         = (const float*)d_in[9];

    const int C = C_DIM;
    const int N = in_sizes[0] / C;   // 20000
    const int E = in_sizes[1];       // 160000

    size_t offb = 0;
    auto alloc = [&](size_t bytes) -> void* {
        void* p = (char*)d_ws + offb;
        offb += (bytes + 255) & ~(size_t)255;
        return p;
    };
    short* nodeL_b = (short*)alloc((size_t)N * C * 2);
    short* nodeR_b = (short*)alloc((size_t)N * C * 2);
    short* Wk_b    = (short*)alloc((size_t)C * C * 2);
    short* Wv_b    = (short*)alloc((size_t)C * C * 2);
    short* Wo_b    = (short*)alloc((size_t)C * C * 2);
    short* Kl      = (short*)alloc((size_t)N * C * 2);
    short* Kr      = (short*)alloc((size_t)N * C * 2);
    short* Vl      = (short*)alloc((size_t)N * C * 2);  // node_right @ Wv^T
    short* Vr      = (short*)alloc((size_t)N * C * 2);  // node_left  @ Wv^T
    short* msgL_b  = (short*)alloc((size_t)N * C * 2);
    short* msgR_b  = (short*)alloc((size_t)N * C * 2);
    float* s_arr   = (float*)alloc((size_t)E * 4);
    int* cnt_l = (int*)alloc((size_t)N * 4);
    int* off_l = (int*)alloc((size_t)(N + 1) * 4);
    int* lst_l = (int*)alloc((size_t)E * 4);
    int* cur_l = (int*)alloc((size_t)N * 4);
    int* cnt_r = (int*)alloc((size_t)N * 4);
    int* off_r = (int*)alloc((size_t)(N + 1) * 4);
    int* lst_r = (int*)alloc((size_t)E * 4);
    int* cur_r = (int*)alloc((size_t)N * 4);

    // 1. converts
    cvt_f32_bf16<<<2048, 256, 0, stream>>>(node_left,  nodeL_b, (long)N * C / 4);
    cvt_f32_bf16<<<2048, 256, 0, stream>>>(node_right, nodeR_b, (long)N * C / 4);
    cvt_f32_bf16<<<256, 256, 0, stream>>>(Wk, Wk_b, (long)C * C / 4);
    cvt_f32_bf16<<<256, 256, 0, stream>>>(Wv, Wv_b, (long)C * C / 4);
    cvt_f32_bf16<<<256, 256, 0, stream>>>(Wo, Wo_b, (long)C * C / 4);

    // 2. projection GEMMs
    dim3 g((N + 127) / 128, C / 128), blk(256);
    gemm_bt<false><<<g, blk, 0, stream>>>(nodeL_b, Wk_b, Kl, nullptr, N, C, C);
    gemm_bt<false><<<g, blk, 0, stream>>>(nodeR_b, Wk_b, Kr, nullptr, N, C, C);
    gemm_bt<false><<<g, blk, 0, stream>>>(nodeR_b, Wv_b, Vl, nullptr, N, C, C);
    gemm_bt<false><<<g, blk, 0, stream>>>(nodeL_b, Wv_b, Vr, nullptr, N, C, C);

    // 3. edge scores
    edge_dot<<<(E + 3) / 4, 256, 0, stream>>>(Kl, Kr, segL, segR, s_arr, E);

    // 4. CSR build (both sides)
    hipMemsetAsync(cnt_l, 0, (size_t)N * 4, stream);
    hipMemsetAsync(cur_l, 0, (size_t)N * 4, stream);
    hipMemsetAsync(cnt_r, 0, (size_t)N * 4, stream);
    hipMemsetAsync(cur_r, 0, (size_t)N * 4, stream);
    count_edges<<<512, 256, 0, stream>>>(segL, cnt_l, E);
    count_edges<<<512, 256, 0, stream>>>(segR, cnt_r, E);
    scan_kernel<<<1, 1024, 0, stream>>>(cnt_l, off_l, N);
    scan_kernel<<<1, 1024, 0, stream>>>(cnt_r, off_r, N);
    fill_csr<<<512, 256, 0, stream>>>(segL, off_l, cur_l, lst_l, E);
    fill_csr<<<512, 256, 0, stream>>>(segR, off_r, cur_r, lst_r, E);

    // 5. per-node softmax + message accumulate
    node_msg<<<(N + 3) / 4, 256, 0, stream>>>(off_l, lst_l, segR, s_arr, Vl, msgL_b, N);
    node_msg<<<(N + 3) / 4, 256, 0, stream>>>(off_r, lst_r, segL, s_arr, Vr, msgR_b, N);

    // 6. output GEMMs with bias + LeakyReLU
    float* outL = (float*)d_out;
    float* outR = outL + (size_t)N * C;
    gemm_bt<true><<<g, blk, 0, stream>>>(msgL_b, Wo_b, outL, bo, N, C, C);
    gemm_bt<true><<<g, blk, 0, stream>>>(msgR_b, Wo_b, outR, bo, N, C, C);
}

// Round 2
// 314.582 us; speedup vs baseline: 1.3895x; 1.3895x over previous
//
#include <hip/hip_runtime.h>

// ---------------------------------------------------------------------------
// MultiHeadAttention graph-attention kernel for MI355X (gfx950).  Round 2.
//   1. cvt kernels: nodes (2 mats) and weights (Wk|Wv concat, Wo) -> bf16
//   2. gemm_bt<false> x2: projL = nodeL @ [Wk;Wv]^T, projR = nodeR @ [Wk;Wv]^T
//      (cols 0-511 = K-proj, cols 512-1023 = V-proj), row stride 1024
//   3. edge_dot: s[e] = dot(projL[segL[e]][:512], projR[segR[e]][:512])/sqrt(C)
//      2 edges per wave for MLP
//   4. merged CSR over 2N nodes (count -> 3-kernel hierarchical scan -> fill)
//   5. node_msg over 2N nodes: online {max, exp-sum, weighted V accum},
//      2-way edge unroll, msg [2N][512] bf16 contiguous
//   6. gemm_bt<true> x1: d_out = LeakyReLU(msg @ Wo^T + bo), M = 2N
// ---------------------------------------------------------------------------

#define C_DIM 512
#define TEMP_INV (1.0f / 22.627416997969522f)   // 1/sqrt(512)

using bf16x8 = __attribute__((ext_vector_type(8))) __bf16;
using s16x8  = __attribute__((ext_vector_type(8))) short;
using s16x4  = __attribute__((ext_vector_type(4))) short;
using f32x4  = __attribute__((ext_vector_type(4))) float;

__device__ __forceinline__ float bf2f(short u) {
    union { unsigned u; float f; } t;
    t.u = ((unsigned)(unsigned short)u) << 16;
    return t.f;
}
__device__ __forceinline__ short f2bf(float f) {
    union { float f; unsigned u; } t;
    t.f = f;
    unsigned r = t.u + 0x7FFFu + ((t.u >> 16) & 1u);  // RNE
    return (short)(r >> 16);
}

// ------------------- fp32 -> bf16 converts (fused pairs) --------------------
// two source arrays, contiguous output
__global__ void cvt2_f32_bf16(const float* __restrict__ inA,
                              const float* __restrict__ inB,
                              short* __restrict__ out, long n4half) {
    long i = (long)blockIdx.x * blockDim.x + threadIdx.x;
    long stride = (long)gridDim.x * blockDim.x;
    long n4 = 2 * n4half;
    for (; i < n4; i += stride) {
        const float4* src = (i < n4half)
            ? reinterpret_cast<const float4*>(inA) + i
            : reinterpret_cast<const float4*>(inB) + (i - n4half);
        float4 v = *src;
        s16x4 o;
        o[0] = f2bf(v.x); o[1] = f2bf(v.y); o[2] = f2bf(v.z); o[3] = f2bf(v.w);
        reinterpret_cast<s16x4*>(out)[i] = o;
    }
}

// three 512x512 weight matrices -> contiguous bf16 [Wk; Wv; Wo]
__global__ void cvt3_f32_bf16(const float* __restrict__ w0,
                              const float* __restrict__ w1,
                              const float* __restrict__ w2,
                              short* __restrict__ out) {
    const long nm = (long)C_DIM * C_DIM / 4;   // float4s per matrix
    long i = (long)blockIdx.x * blockDim.x + threadIdx.x;
    long stride = (long)gridDim.x * blockDim.x;
    for (; i < 3 * nm; i += stride) {
        const float* src = (i < nm) ? w0 : (i < 2 * nm) ? w1 : w2;
        long j = (i < nm) ? i : (i < 2 * nm) ? i - nm : i - 2 * nm;
        float4 v = reinterpret_cast<const float4*>(src)[j];
        s16x4 o;
        o[0] = f2bf(v.x); o[1] = f2bf(v.y); o[2] = f2bf(v.z); o[3] = f2bf(v.w);
        reinterpret_cast<s16x4*>(out)[i] = o;
    }
}

// ------------------------------- bf16 GEMM ---------------------------------
// C[M,N] = A[M,K] @ B[N,K]^T. 128x128 tile, BK=32, 4 waves (2x2).
// EPI=false: C bf16. EPI=true: C fp32, += bias, LeakyReLU.
template <bool EPI>
__global__ __launch_bounds__(256, 2)
void gemm_bt(const short* __restrict__ A, const short* __restrict__ B,
             void* __restrict__ Cp, const float* __restrict__ bias,
             int M, int N, int K) {
    __shared__ short As[128 * 32];
    __shared__ short Bs[128 * 32];

    const int tid  = threadIdx.x;
    const int lane = tid & 63;
    const int wid  = tid >> 6;
    const int bm   = blockIdx.x * 128;
    const int bn   = blockIdx.y * 128;
    const int wm   = (wid >> 1) * 64;
    const int wn   = (wid & 1) * 64;

    f32x4 acc[4][4] = {};

    const int lrow  = lane & 15;
    const int khalf = lane >> 4;

    for (int k0 = 0; k0 < K; k0 += 32) {
#pragma unroll
        for (int i = 0; i < 2; ++i) {
            int c   = i * 256 + tid;
            int row = c >> 2;
            int kb  = (c & 3) * 8;
            int wave_chunk = i * 256 + (tid & ~63);
            {
                int grow = bm + row; if (grow >= M) grow = M - 1;
                const short* src = A + (size_t)grow * K + k0 + kb;
                __builtin_amdgcn_global_load_lds(
                    (__attribute__((address_space(1))) void*)src,
                    (__attribute__((address_space(3))) void*)((char*)As + wave_chunk * 16),
                    16, 0, 0);
            }
            {
                int grow = bn + row; if (grow >= N) grow = N - 1;
                const short* src = B + (size_t)grow * K + k0 + kb;
                __builtin_amdgcn_global_load_lds(
                    (__attribute__((address_space(1))) void*)src,
                    (__attribute__((address_space(3))) void*)((char*)Bs + wave_chunk * 16),
                    16, 0, 0);
            }
        }
        __syncthreads();

        bf16x8 af[4], bfr[4];
#pragma unroll
        for (int m = 0; m < 4; ++m)
            af[m] = *(const bf16x8*)&As[(wm + m * 16 + lrow) * 32 + khalf * 8];
#pragma unroll
        for (int n = 0; n < 4; ++n)
            bfr[n] = *(const bf16x8*)&Bs[(wn + n * 16 + lrow) * 32 + khalf * 8];

#pragma unroll
        for (int m = 0; m < 4; ++m)
#pragma unroll
            for (int n = 0; n < 4; ++n)
                acc[m][n] = __builtin_amdgcn_mfma_f32_16x16x32_bf16(
                    af[m], bfr[n], acc[m][n], 0, 0, 0);
        __syncthreads();
    }

    const int crow0 = (lane >> 4) * 4;
    const int ccol  = lane & 15;
#pragma unroll
    for (int m = 0; m < 4; ++m) {
#pragma unroll
        for (int n = 0; n < 4; ++n) {
            int col = bn + wn + n * 16 + ccol;
#pragma unroll
            for (int r = 0; r < 4; ++r) {
                int row = bm + wm + m * 16 + crow0 + r;
                if (row < M) {
                    float v = acc[m][n][r];
                    if (EPI) {
                        v += bias[col];
                        v = v >= 0.f ? v : 0.01f * v;
                        ((float*)Cp)[(size_t)row * N + col] = v;
                    } else {
                        ((short*)Cp)[(size_t)row * N + col] = f2bf(v);
                    }
                }
            }
        }
    }
}

// --------------------------- per-edge dot product ---------------------------
// 2 edges per wave (doubles loads in flight); rows have stride 1024 (K in
// cols 0-511 of the fused projection).
__global__ void edge_dot(const short* __restrict__ projL, const short* __restrict__ projR,
                         const int* __restrict__ segL, const int* __restrict__ segR,
                         float* __restrict__ s, int E) {
    int e0 = blockIdx.x * 8 + (threadIdx.x >> 6) * 2;
    if (e0 >= E) return;
    int lane = threadIdx.x & 63;
    bool has1 = (e0 + 1) < E;
    int e1 = has1 ? e0 + 1 : e0;

    const short* a0 = projL + (size_t)segL[e0] * 1024 + lane * 8;
    const short* b0 = projR + (size_t)segR[e0] * 1024 + lane * 8;
    const short* a1 = projL + (size_t)segL[e1] * 1024 + lane * 8;
    const short* b1 = projR + (size_t)segR[e1] * 1024 + lane * 8;
    s16x8 va0 = *(const s16x8*)a0;
    s16x8 vb0 = *(const s16x8*)b0;
    s16x8 va1 = *(const s16x8*)a1;
    s16x8 vb1 = *(const s16x8*)b1;

    float s0 = 0.f, s1 = 0.f;
#pragma unroll
    for (int j = 0; j < 8; ++j) {
        s0 += bf2f(va0[j]) * bf2f(vb0[j]);
        s1 += bf2f(va1[j]) * bf2f(vb1[j]);
    }
#pragma unroll
    for (int o = 32; o > 0; o >>= 1) {
        s0 += __shfl_xor(s0, o, 64);
        s1 += __shfl_xor(s1, o, 64);
    }
    if (lane == 0) {
        s[e0] = s0 * TEMP_INV;
        if (has1) s[e1] = s1 * TEMP_INV;
    }
}

// ------------------------------- CSR build ---------------------------------
// merged over 2N virtual nodes: node n<N <- segL side, node N+n <- segR side
__global__ void count_edges2(const int* __restrict__ segL, const int* __restrict__ segR,
                             int* __restrict__ cnt, int E, int N) {
    int i = blockIdx.x * blockDim.x + threadIdx.x;
    int st = gridDim.x * blockDim.x;
    for (; i < E; i += st) {
        atomicAdd(&cnt[segL[i]], 1);
        atomicAdd(&cnt[N + segR[i]], 1);
    }
}

// hierarchical scan: per-block inclusive scan + block sums
__global__ void scan_blocks(const int* __restrict__ cnt, int* __restrict__ off,
                            int* __restrict__ bsum, int n) {
    __shared__ int ws[4];
    int tid = threadIdx.x, lane = tid & 63, wid = tid >> 6;
    int i = blockIdx.x * 256 + tid;
    int x = (i < n) ? cnt[i] : 0;
    int v = x;
#pragma unroll
    for (int d = 1; d < 64; d <<= 1) {
        int t = __shfl_up(v, d, 64);
        if (lane >= d) v += t;
    }
    if (lane == 63) ws[wid] = v;
    __syncthreads();
    int woff = 0;
    for (int w = 0; w < wid; ++w) woff += ws[w];
    v += woff;
    if (i < n) off[i + 1] = v;
    if (tid == 255) bsum[blockIdx.x] = v;
}

// scan of block sums (nb <= 256), in-place -> exclusive prefix
__global__ void scan_tops(int* __restrict__ bsum, int nb) {
    __shared__ int ws[4];
    int tid = threadIdx.x, lane = tid & 63, wid = tid >> 6;
    int x = (tid < nb) ? bsum[tid] : 0;
    int v = x;
#pragma unroll
    for (int d = 1; d < 64; d <<= 1) {
        int t = __shfl_up(v, d, 64);
        if (lane >= d) v += t;
    }
    if (lane == 63) ws[wid] = v;
    __syncthreads();
    int woff = 0;
    for (int w = 0; w < wid; ++w) woff += ws[w];
    v += woff;
    if (tid < nb) bsum[tid] = v - x;   // exclusive
}

// apply block offsets; zero cnt for reuse as fill cursor; set off[0]
__global__ void scan_apply(int* __restrict__ off, const int* __restrict__ bsum,
                           int* __restrict__ cnt, int n) {
    int i = blockIdx.x * 256 + threadIdx.x;
    if (i < n) {
        off[i + 1] += bsum[blockIdx.x];
        cnt[i] = 0;
    }
    if (i == 0) off[0] = 0;
}

__global__ void fill_csr2(const int* __restrict__ segL, const int* __restrict__ segR,
                          const int* __restrict__ off, int* __restrict__ cur,
                          int* __restrict__ lst, int E, int N) {
    int i = blockIdx.x * blockDim.x + threadIdx.x;
    int st = gridDim.x * blockDim.x;
    for (; i < E; i += st) {
        int nl = segL[i];
        int pl = off[nl] + atomicAdd(&cur[nl], 1);
        lst[pl] = i;
        int nr = N + segR[i];
        int pr = off[nr] + atomicAdd(&cur[nr], 1);
        lst[pr] = i;
    }
}

// ------------------- per-node softmax + weighted V sum ----------------------
// one wave per virtual node (2N total); lane owns 8 channels.
// 2-way unrolled accumulate for memory-level parallelism.
__global__ void node_msg(const int* __restrict__ off, const int* __restrict__ lst,
                         const int* __restrict__ segL, const int* __restrict__ segR,
                         const float* __restrict__ s,
                         const short* __restrict__ projL, const short* __restrict__ projR,
                         short* __restrict__ msg, int N) {
    int n = blockIdx.x * 4 + (threadIdx.x >> 6);
    if (n >= 2 * N) return;
    int lane = threadIdx.x & 63;
    int beg = off[n], end = off[n + 1];
    short* orow = msg + (size_t)n * C_DIM + lane * 8;
    if (beg == end) {
        s16x8 zv = {};
        *(s16x8*)orow = zv;
        return;
    }
    bool left = n < N;
    const int* oseg = left ? segR : segL;
    const short* Vb = (left ? projR : projL) + 512;   // V slice, stride 1024

    // max pass (4-way unrolled)
    float m = -1e30f;
    int i = beg;
    for (; i + 3 < end; i += 4) {
        float s0 = s[lst[i]], s1 = s[lst[i + 1]];
        float s2 = s[lst[i + 2]], s3 = s[lst[i + 3]];
        m = fmaxf(m, fmaxf(fmaxf(s0, s1), fmaxf(s2, s3)));
    }
    for (; i < end; ++i) m = fmaxf(m, s[lst[i]]);

    // accumulate pass (2-way unrolled: 2 independent V-row loads in flight)
    float acc[8] = {};
    float z = 0.f;
    i = beg;
    for (; i + 1 < end; i += 2) {
        int e0 = lst[i], e1 = lst[i + 1];
        const s16x8 v0 = *(const s16x8*)(Vb + (size_t)oseg[e0] * 1024 + lane * 8);
        const s16x8 v1 = *(const s16x8*)(Vb + (size_t)oseg[e1] * 1024 + lane * 8);
        float w0 = __expf(s[e0] - m);
        float w1 = __expf(s[e1] - m);
        z += w0 + w1;
#pragma unroll
        for (int j = 0; j < 8; ++j) {
            acc[j] += w0 * bf2f(v0[j]);
            acc[j] += w1 * bf2f(v1[j]);
        }
    }
    if (i < end) {
        int e0 = lst[i];
        const s16x8 v0 = *(const s16x8*)(Vb + (size_t)oseg[e0] * 1024 + lane * 8);
        float w0 = __expf(s[e0] - m);
        z += w0;
#pragma unroll
        for (int j = 0; j < 8; ++j) acc[j] += w0 * bf2f(v0[j]);
    }
    float inv = 1.f / z;
    s16x8 ov;
#pragma unroll
    for (int j = 0; j < 8; ++j) ov[j] = f2bf(acc[j] * inv);
    *(s16x8*)orow = ov;
}

// ------------------------------- launcher ----------------------------------
extern "C" void kernel_launch(void* const* d_in, const int* in_sizes, int n_in,
                              void* d_out, int out_size, void* d_ws, size_t ws_size,
                              hipStream_t stream) {
    const float* node_left  = (const float*)d_in[0];
    const int*   segL       = (const int*)d_in[1];
    const float* node_right = (const float*)d_in[3];
    const int*   segR       = (const int*)d_in[4];
    const float* Wk         = (const float*)d_in[6];
    const float* Wv         = (const float*)d_in[7];
    const float* Wo         = (const float*)d_in[8];
    const float* bo         = (const float*)d_in[9];

    const int C = C_DIM;
    const int N = in_sizes[0] / C;   // 20000
    const int E = in_sizes[1];       // 160000
    const int NN2 = 2 * N;

    size_t offb = 0;
    auto alloc = [&](size_t bytes) -> void* {
        void* p = (char*)d_ws + offb;
        offb += (bytes + 255) & ~(size_t)255;
        return p;
    };
    // node bf16: L then R contiguous (cvt2 writes as one array)
    short* nodeLR_b = (short*)alloc((size_t)NN2 * C * 2);
    short* nodeL_b  = nodeLR_b;
    short* nodeR_b  = nodeLR_b + (size_t)N * C;
    // weights: [Wk; Wv; Wo] contiguous bf16
    short* W_b   = (short*)alloc((size_t)3 * C * C * 2);
    short* Wkv_b = W_b;                       // [1024][512]
    short* Wo_b  = W_b + (size_t)2 * C * C;   // [512][512]
    // fused projections [N][1024]: cols 0-511 K, 512-1023 V
    short* projL = (short*)alloc((size_t)N * 1024 * 2);
    short* projR = (short*)alloc((size_t)N * 1024 * 2);
    // messages [2N][512] contiguous (direct GEMM A / output rows)
    short* msg   = (short*)alloc((size_t)NN2 * C * 2);
    float* s_arr = (float*)alloc((size_t)E * 4);
    int* cnt  = (int*)alloc((size_t)NN2 * 4);        // also fill cursor
    int* off  = (int*)alloc((size_t)(NN2 + 1) * 4);
    int* lst  = (int*)alloc((size_t)2 * E * 4);
    int* bsum = (int*)alloc(256 * 4);

    const int nsb = (NN2 + 255) / 256;   // scan blocks (157 <= 256)

    // 1. converts
    cvt2_f32_bf16<<<2048, 256, 0, stream>>>(node_left, node_right, nodeLR_b,
                                            (long)N * C / 4);
    cvt3_f32_bf16<<<768, 256, 0, stream>>>(Wk, Wv, Wo, W_b);

    // 2. projection GEMMs (fused K|V, N=1024)
    dim3 gp((N + 127) / 128, 1024 / 128), blk(256);
    gemm_bt<false><<<gp, blk, 0, stream>>>(nodeL_b, Wkv_b, projL, nullptr, N, 1024, C);
    gemm_bt<false><<<gp, blk, 0, stream>>>(nodeR_b, Wkv_b, projR, nullptr, N, 1024, C);

    // 3. edge scores
    edge_dot<<<(E + 7) / 8, 256, 0, stream>>>(projL, projR, segL, segR, s_arr, E);

    // 4. merged CSR over 2N nodes
    hipMemsetAsync(cnt, 0, (size_t)NN2 * 4, stream);
    count_edges2<<<512, 256, 0, stream>>>(segL, segR, cnt, E, N);
    scan_blocks<<<nsb, 256, 0, stream>>>(cnt, off, bsum, NN2);
    scan_tops<<<1, 256, 0, stream>>>(bsum, nsb);
    scan_apply<<<nsb, 256, 0, stream>>>(off, bsum, cnt, NN2);
    fill_csr2<<<512, 256, 0, stream>>>(segL, segR, off, cnt, lst, E, N);

    // 5. per-node softmax + message accumulate (both sides)
    node_msg<<<(NN2 + 3) / 4, 256, 0, stream>>>(off, lst, segL, segR, s_arr,
                                                projL, projR, msg, N);

    // 6. single output GEMM with bias + LeakyReLU, writes d_out directly
    dim3 go((NN2 + 127) / 128, C / 128);
    gemm_bt<true><<<go, blk, 0, stream>>>(msg, Wo_b, (float*)d_out, bo, NN2, C, C);
}

// Round 3
// 276.523 us; speedup vs baseline: 1.5807x; 1.1376x over previous
//
#include <hip/hip_runtime.h>

// ---------------------------------------------------------------------------
// MultiHeadAttention graph-attention kernel for MI355X (gfx950).  Round 3.
//   1. cvt: nodes (L|R contiguous) and weights ([Wk;Wv;Wo]) -> bf16
//   2. gemm_bt<false> x1: proj[2N][1024] = nodeLR @ [Wk;Wv]^T
//      (2-phase double-buffered, LDS-swizzled, XCD-chunked block swizzle)
//   3. edge_dot: s[e] = dot(K_L[segL[e]], K_R[segR[e]]) / sqrt(C)
//   4. merged CSR over 2N nodes (count -> hierarchical scan -> fill)
//   5. node_msg over 2N nodes, 4-way unrolled V accumulate
//   6. gemm_bt<true> x1: d_out = LeakyReLU(msg @ Wo^T + bo), M = 2N
// ---------------------------------------------------------------------------

#define C_DIM 512
#define TEMP_INV (1.0f / 22.627416997969522f)   // 1/sqrt(512)

using bf16x8 = __attribute__((ext_vector_type(8))) __bf16;
using s16x8  = __attribute__((ext_vector_type(8))) short;
using s16x4  = __attribute__((ext_vector_type(4))) short;
using f32x4  = __attribute__((ext_vector_type(4))) float;

__device__ __forceinline__ float bf2f(short u) {
    union { unsigned u; float f; } t;
    t.u = ((unsigned)(unsigned short)u) << 16;
    return t.f;
}
__device__ __forceinline__ short f2bf(float f) {
    union { float f; unsigned u; } t;
    t.f = f;
    unsigned r = t.u + 0x7FFFu + ((t.u >> 16) & 1u);  // RNE
    return (short)(r >> 16);
}

// ------------------- fp32 -> bf16 converts (fused) --------------------------
__global__ void cvt2_f32_bf16(const float* __restrict__ inA,
                              const float* __restrict__ inB,
                              short* __restrict__ out, long n4half) {
    long i = (long)blockIdx.x * blockDim.x + threadIdx.x;
    long stride = (long)gridDim.x * blockDim.x;
    long n4 = 2 * n4half;
    for (; i < n4; i += stride) {
        const float4* src = (i < n4half)
            ? reinterpret_cast<const float4*>(inA) + i
            : reinterpret_cast<const float4*>(inB) + (i - n4half);
        float4 v = *src;
        s16x4 o;
        o[0] = f2bf(v.x); o[1] = f2bf(v.y); o[2] = f2bf(v.z); o[3] = f2bf(v.w);
        reinterpret_cast<s16x4*>(out)[i] = o;
    }
}

__global__ void cvt3_f32_bf16(const float* __restrict__ w0,
                              const float* __restrict__ w1,
                              const float* __restrict__ w2,
                              short* __restrict__ out) {
    const long nm = (long)C_DIM * C_DIM / 4;
    long i = (long)blockIdx.x * blockDim.x + threadIdx.x;
    long stride = (long)gridDim.x * blockDim.x;
    for (; i < 3 * nm; i += stride) {
        const float* src = (i < nm) ? w0 : (i < 2 * nm) ? w1 : w2;
        long j = (i < nm) ? i : (i < 2 * nm) ? i - nm : i - 2 * nm;
        float4 v = reinterpret_cast<const float4*>(src)[j];
        s16x4 o;
        o[0] = f2bf(v.x); o[1] = f2bf(v.y); o[2] = f2bf(v.z); o[3] = f2bf(v.w);
        reinterpret_cast<s16x4*>(out)[i] = o;
    }
}

// ------------------------------- bf16 GEMM ---------------------------------
// C[M,N] = A[M,K] @ B[N,K]^T. 128x128 tile, BK=32, 4 waves (2x2).
// 2-phase double-buffered (counted vmcnt, raw barriers), LDS chunk-XOR
// swizzle (source-side pre-swizzle, rule #21), bijective XCD block swizzle.
template <bool EPI>
__global__ __launch_bounds__(256, 4)
void gemm_bt(const short* __restrict__ A, const short* __restrict__ B,
             void* __restrict__ Cp, const float* __restrict__ bias,
             int M, int N, int K, int nn, int total) {
    __shared__ short As[2][128 * 32];
    __shared__ short Bs[2][128 * 32];

    // ---- bijective XCD-chunked block swizzle (m204) ----
    const int bid = blockIdx.x;
    const int q = total >> 3, r = total & 7;
    const int xcd = bid & 7, idx = bid >> 3;
    const int swz = (xcd < r ? xcd * (q + 1) : r * (q + 1) + (xcd - r) * q) + idx;
    const int bm = (swz / nn) * 128;
    const int bn = (swz % nn) * 128;

    const int tid  = threadIdx.x;
    const int lane = tid & 63;
    const int wid  = tid >> 6;
    const int wm   = (wid >> 1) * 64;
    const int wn   = (wid & 1) * 64;
    const int lrow  = lane & 15;
    const int khalf = lane >> 4;

    // stage one 128x32 A-tile + B-tile into buffer `b`, K-offset k0.
    // LDS chunk c (16B) holds global k-chunk (c&3)^(row&3)  [bank swizzle]
    auto stage = [&](short* dA, short* dB, int k0) {
#pragma unroll
        for (int j = 0; j < 2; ++j) {
            int c   = j * 256 + tid;
            int row = c >> 2;
            int kc  = (c & 3) ^ (row & 3);
            int wave_base = (j * 256 + (tid & ~63)) * 16;   // bytes
            {
                int grow = bm + row; if (grow >= M) grow = M - 1;
                const short* src = A + (size_t)grow * K + k0 + kc * 8;
                __builtin_amdgcn_global_load_lds(
                    (__attribute__((address_space(1))) void*)src,
                    (__attribute__((address_space(3))) void*)((char*)dA + wave_base),
                    16, 0, 0);
            }
            {
                int grow = bn + row; if (grow >= N) grow = N - 1;
                const short* src = B + (size_t)grow * K + k0 + kc * 8;
                __builtin_amdgcn_global_load_lds(
                    (__attribute__((address_space(1))) void*)src,
                    (__attribute__((address_space(3))) void*)((char*)dB + wave_base),
                    16, 0, 0);
            }
        }
    };

    f32x4 acc[4][4] = {};
    const int nt = K >> 5;

    stage(As[0], Bs[0], 0);

    for (int t = 0; t < nt; ++t) {
        const int cur = t & 1;
        if (t + 1 < nt) {
            stage(As[cur ^ 1], Bs[cur ^ 1], (t + 1) << 5);
            asm volatile("s_waitcnt vmcnt(4)" ::: "memory");  // tile t landed
        } else {
            asm volatile("s_waitcnt vmcnt(0)" ::: "memory");
        }
        __builtin_amdgcn_s_barrier();                         // buf[cur] ready

        const short* as = As[cur];
        const short* bs = Bs[cur];
        bf16x8 af[4], bfr[4];
#pragma unroll
        for (int m = 0; m < 4; ++m) {
            int row = wm + m * 16 + lrow;
            af[m] = *(const bf16x8*)&as[row * 32 + ((khalf ^ (row & 3)) * 8)];
        }
#pragma unroll
        for (int n = 0; n < 4; ++n) {
            int row = wn + n * 16 + lrow;
            bfr[n] = *(const bf16x8*)&bs[row * 32 + ((khalf ^ (row & 3)) * 8)];
        }
        // drain ds_reads, then release buf[cur] for next iter's stage
        asm volatile("s_waitcnt lgkmcnt(0)" ::: "memory");
        __builtin_amdgcn_sched_barrier(0);
        __builtin_amdgcn_s_barrier();

#pragma unroll
        for (int m = 0; m < 4; ++m)
#pragma unroll
            for (int n = 0; n < 4; ++n)
                acc[m][n] = __builtin_amdgcn_mfma_f32_16x16x32_bf16(
                    af[m], bfr[n], acc[m][n], 0, 0, 0);
    }

    // ---- epilogue: D mapping col=lane&15, row=(lane>>4)*4+r  [m89] ----
    const int crow0 = (lane >> 4) * 4;
    const int ccol  = lane & 15;
#pragma unroll
    for (int m = 0; m < 4; ++m) {
#pragma unroll
        for (int n = 0; n < 4; ++n) {
            int col = bn + wn + n * 16 + ccol;
#pragma unroll
            for (int r2 = 0; r2 < 4; ++r2) {
                int row = bm + wm + m * 16 + crow0 + r2;
                if (row < M) {
                    float v = acc[m][n][r2];
                    if (EPI) {
                        v += bias[col];
                        v = v >= 0.f ? v : 0.01f * v;
                        ((float*)Cp)[(size_t)row * N + col] = v;
                    } else {
                        ((short*)Cp)[(size_t)row * N + col] = f2bf(v);
                    }
                }
            }
        }
    }
}

// --------------------------- per-edge dot product ---------------------------
__global__ void edge_dot(const short* __restrict__ projL, const short* __restrict__ projR,
                         const int* __restrict__ segL, const int* __restrict__ segR,
                         float* __restrict__ s, int E) {
    int e0 = blockIdx.x * 8 + (threadIdx.x >> 6) * 2;
    if (e0 >= E) return;
    int lane = threadIdx.x & 63;
    bool has1 = (e0 + 1) < E;
    int e1 = has1 ? e0 + 1 : e0;

    s16x8 va0 = *(const s16x8*)(projL + (size_t)segL[e0] * 1024 + lane * 8);
    s16x8 vb0 = *(const s16x8*)(projR + (size_t)segR[e0] * 1024 + lane * 8);
    s16x8 va1 = *(const s16x8*)(projL + (size_t)segL[e1] * 1024 + lane * 8);
    s16x8 vb1 = *(const s16x8*)(projR + (size_t)segR[e1] * 1024 + lane * 8);

    float s0 = 0.f, s1 = 0.f;
#pragma unroll
    for (int j = 0; j < 8; ++j) {
        s0 += bf2f(va0[j]) * bf2f(vb0[j]);
        s1 += bf2f(va1[j]) * bf2f(vb1[j]);
    }
#pragma unroll
    for (int o = 32; o > 0; o >>= 1) {
        s0 += __shfl_xor(s0, o, 64);
        s1 += __shfl_xor(s1, o, 64);
    }
    if (lane == 0) {
        s[e0] = s0 * TEMP_INV;
        if (has1) s[e1] = s1 * TEMP_INV;
    }
}

// ------------------------------- CSR build ---------------------------------
__global__ void count_edges2(const int* __restrict__ segL, const int* __restrict__ segR,
                             int* __restrict__ cnt, int E, int N) {
    int i = blockIdx.x * blockDim.x + threadIdx.x;
    int st = gridDim.x * blockDim.x;
    for (; i < E; i += st) {
        atomicAdd(&cnt[segL[i]], 1);
        atomicAdd(&cnt[N + segR[i]], 1);
    }
}

__global__ void scan_blocks(const int* __restrict__ cnt, int* __restrict__ off,
                            int* __restrict__ bsum, int n) {
    __shared__ int ws[4];
    int tid = threadIdx.x, lane = tid & 63, wid = tid >> 6;
    int i = blockIdx.x * 256 + tid;
    int x = (i < n) ? cnt[i] : 0;
    int v = x;
#pragma unroll
    for (int d = 1; d < 64; d <<= 1) {
        int t = __shfl_up(v, d, 64);
        if (lane >= d) v += t;
    }
    if (lane == 63) ws[wid] = v;
    __syncthreads();
    int woff = 0;
    for (int w = 0; w < wid; ++w) woff += ws[w];
    v += woff;
    if (i < n) off[i + 1] = v;
    if (tid == 255) bsum[blockIdx.x] = v;
}

__global__ void scan_tops(int* __restrict__ bsum, int nb) {
    __shared__ int ws[4];
    int tid = threadIdx.x, lane = tid & 63, wid = tid >> 6;
    int x = (tid < nb) ? bsum[tid] : 0;
    int v = x;
#pragma unroll
    for (int d = 1; d < 64; d <<= 1) {
        int t = __shfl_up(v, d, 64);
        if (lane >= d) v += t;
    }
    if (lane == 63) ws[wid] = v;
    __syncthreads();
    int woff = 0;
    for (int w = 0; w < wid; ++w) woff += ws[w];
    v += woff;
    if (tid < nb) bsum[tid] = v - x;
}

__global__ void scan_apply(int* __restrict__ off, const int* __restrict__ bsum,
                           int* __restrict__ cnt, int n) {
    int i = blockIdx.x * 256 + threadIdx.x;
    if (i < n) {
        off[i + 1] += bsum[blockIdx.x];
        cnt[i] = 0;
    }
    if (i == 0) off[0] = 0;
}

__global__ void fill_csr2(const int* __restrict__ segL, const int* __restrict__ segR,
                          const int* __restrict__ off, int* __restrict__ cur,
                          int* __restrict__ lst, int E, int N) {
    int i = blockIdx.x * blockDim.x + threadIdx.x;
    int st = gridDim.x * blockDim.x;
    for (; i < E; i += st) {
        int nl = segL[i];
        int pl = off[nl] + atomicAdd(&cur[nl], 1);
        lst[pl] = i;
        int nr = N + segR[i];
        int pr = off[nr] + atomicAdd(&cur[nr], 1);
        lst[pr] = i;
    }
}

// ------------------- per-node softmax + weighted V sum ----------------------
__global__ void node_msg(const int* __restrict__ off, const int* __restrict__ lst,
                         const int* __restrict__ segL, const int* __restrict__ segR,
                         const float* __restrict__ s,
                         const short* __restrict__ projL, const short* __restrict__ projR,
                         short* __restrict__ msg, int N) {
    int n = blockIdx.x * 4 + (threadIdx.x >> 6);
    if (n >= 2 * N) return;
    int lane = threadIdx.x & 63;
    int beg = off[n], end = off[n + 1];
    short* orow = msg + (size_t)n * C_DIM + lane * 8;
    if (beg == end) {
        s16x8 zv = {};
        *(s16x8*)orow = zv;
        return;
    }
    bool left = n < N;
    const int* oseg = left ? segR : segL;
    const short* Vb = (left ? projR : projL) + 512;   // V slice, stride 1024

    // max pass (4-way unrolled)
    float m = -1e30f;
    int i = beg;
    for (; i + 3 < end; i += 4) {
        float s0 = s[lst[i]], s1 = s[lst[i + 1]];
        float s2 = s[lst[i + 2]], s3 = s[lst[i + 3]];
        m = fmaxf(m, fmaxf(fmaxf(s0, s1), fmaxf(s2, s3)));
    }
    for (; i < end; ++i) m = fmaxf(m, s[lst[i]]);

    // accumulate pass (4-way unrolled: 4 independent V-row loads in flight)
    float acc[8] = {};
    float z = 0.f;
    i = beg;
    for (; i + 3 < end; i += 4) {
        int e0 = lst[i], e1 = lst[i + 1], e2 = lst[i + 2], e3 = lst[i + 3];
        const s16x8 v0 = *(const s16x8*)(Vb + (size_t)oseg[e0] * 1024 + lane * 8);
        const s16x8 v1 = *(const s16x8*)(Vb + (size_t)oseg[e1] * 1024 + lane * 8);
        const s16x8 v2 = *(const s16x8*)(Vb + (size_t)oseg[e2] * 1024 + lane * 8);
        const s16x8 v3 = *(const s16x8*)(Vb + (size_t)oseg[e3] * 1024 + lane * 8);
        float w0 = __expf(s[e0] - m);
        float w1 = __expf(s[e1] - m);
        float w2 = __expf(s[e2] - m);
        float w3 = __expf(s[e3] - m);
        z += (w0 + w1) + (w2 + w3);
#pragma unroll
        for (int j = 0; j < 8; ++j) {
            acc[j] += w0 * bf2f(v0[j]) + w1 * bf2f(v1[j]);
            acc[j] += w2 * bf2f(v2[j]) + w3 * bf2f(v3[j]);
        }
    }
    for (; i < end; ++i) {
        int e0 = lst[i];
        const s16x8 v0 = *(const s16x8*)(Vb + (size_t)oseg[e0] * 1024 + lane * 8);
        float w0 = __expf(s[e0] - m);
        z += w0;
#pragma unroll
        for (int j = 0; j < 8; ++j) acc[j] += w0 * bf2f(v0[j]);
    }
    float inv = 1.f / z;
    s16x8 ov;
#pragma unroll
    for (int j = 0; j < 8; ++j) ov[j] = f2bf(acc[j] * inv);
    *(s16x8*)orow = ov;
}

// ------------------------------- launcher ----------------------------------
extern "C" void kernel_launch(void* const* d_in, const int* in_sizes, int n_in,
                              void* d_out, int out_size, void* d_ws, size_t ws_size,
                              hipStream_t stream) {
    const float* node_left  = (const float*)d_in[0];
    const int*   segL       = (const int*)d_in[1];
    const float* node_right = (const float*)d_in[3];
    const int*   segR       = (const int*)d_in[4];
    const float* Wk         = (const float*)d_in[6];
    const float* Wv         = (const float*)d_in[7];
    const float* Wo         = (const float*)d_in[8];
    const float* bo         = (const float*)d_in[9];

    const int C = C_DIM;
    const int N = in_sizes[0] / C;   // 20000
    const int E = in_sizes[1];       // 160000
    const int NN2 = 2 * N;

    size_t offb = 0;
    auto alloc = [&](size_t bytes) -> void* {
        void* p = (char*)d_ws + offb;
        offb += (bytes + 255) & ~(size_t)255;
        return p;
    };
    short* nodeLR_b = (short*)alloc((size_t)NN2 * C * 2);     // [2N][512]
    short* W_b   = (short*)alloc((size_t)3 * C * C * 2);      // [Wk;Wv;Wo]
    short* Wkv_b = W_b;                                       // [1024][512]
    short* Wo_b  = W_b + (size_t)2 * C * C;                   // [512][512]
    short* proj  = (short*)alloc((size_t)NN2 * 1024 * 2);     // [2N][1024]
    short* projL = proj;
    short* projR = proj + (size_t)N * 1024;
    short* msg   = (short*)alloc((size_t)NN2 * C * 2);        // [2N][512]
    float* s_arr = (float*)alloc((size_t)E * 4);
    int* cnt  = (int*)alloc((size_t)NN2 * 4);
    int* off  = (int*)alloc((size_t)(NN2 + 1) * 4);
    int* lst  = (int*)alloc((size_t)2 * E * 4);
    int* bsum = (int*)alloc(256 * 4);

    const int nsb = (NN2 + 255) / 256;

    // 1. converts
    cvt2_f32_bf16<<<2048, 256, 0, stream>>>(node_left, node_right, nodeLR_b,
                                            (long)N * C / 4);
    cvt3_f32_bf16<<<768, 256, 0, stream>>>(Wk, Wv, Wo, W_b);

    // 2. fused projection GEMM: proj[2N][1024] = nodeLR @ [Wk;Wv]^T
    {
        int nm = (NN2 + 127) / 128, nn = 1024 / 128;
        int total = nm * nn;
        gemm_bt<false><<<total, 256, 0, stream>>>(nodeLR_b, Wkv_b, proj, nullptr,
                                                  NN2, 1024, C, nn, total);
    }

    // 3. edge scores
    edge_dot<<<(E + 7) / 8, 256, 0, stream>>>(projL, projR, segL, segR, s_arr, E);

    // 4. merged CSR over 2N nodes
    hipMemsetAsync(cnt, 0, (size_t)NN2 * 4, stream);
    count_edges2<<<512, 256, 0, stream>>>(segL, segR, cnt, E, N);
    scan_blocks<<<nsb, 256, 0, stream>>>(cnt, off, bsum, NN2);
    scan_tops<<<1, 256, 0, stream>>>(bsum, nsb);
    scan_apply<<<nsb, 256, 0, stream>>>(off, bsum, cnt, NN2);
    fill_csr2<<<512, 256, 0, stream>>>(segL, segR, off, cnt, lst, E, N);

    // 5. per-node softmax + message accumulate (both sides)
    node_msg<<<(NN2 + 3) / 4, 256, 0, stream>>>(off, lst, segL, segR, s_arr,
                                                projL, projR, msg, N);

    // 6. output GEMM with bias + LeakyReLU -> d_out
    {
        int nm = (NN2 + 127) / 128, nn = C / 128;
        int total = nm * nn;
        gemm_bt<true><<<total, 256, 0, stream>>>(msg, Wo_b, (float*)d_out, bo,
                                                 NN2, C, C, nn, total);
    }
}